// Round 1
// baseline (5475.508 us; speedup 1.0000x reference)
//
#include <hip/hip_runtime.h>
#include <hip/hip_bf16.h>

#define NG 512  // NUM_GRAPHS

// ---------------- degree / normalization ----------------

__global__ void k_count(const int* __restrict__ dst, int* __restrict__ cnt, int E) {
    int i = blockIdx.x * blockDim.x + threadIdx.x;
    if (i < E) atomicAdd(&cnt[dst[i]], 1);
}

__global__ void k_dinv(const int* __restrict__ cnt, float* __restrict__ dinv, int N) {
    int i = blockIdx.x * blockDim.x + threadIdx.x;
    if (i < N) dinv[i] = rsqrtf((float)cnt[i] + 1.0f);  // +1 self-loop; deg>=1 always
}

// ---------------- dense matmul (small channel counts, per-thread dot) ----------------

template <int CIN, int COUT>
__global__ void k_matmul(const float* __restrict__ in, const float* __restrict__ W,
                         float* __restrict__ h, int N) {
    int idx = blockIdx.x * blockDim.x + threadIdx.x;
    int n = idx / COUT;
    if (n >= N) return;
    int c = idx - n * COUT;
    float acc = 0.f;
#pragma unroll
    for (int k = 0; k < CIN; ++k) acc = fmaf(in[n * CIN + k], W[k * COUT + c], acc);
    h[idx] = acc;  // idx == n*COUT + c
}

// ---------------- self-loop init: out[n] = dinv[n]^2 * h[n] ----------------

template <int C>
__global__ void k_selfinit(const float* __restrict__ h, const float* __restrict__ dinv,
                           float* __restrict__ out, int N) {
    int idx = blockIdx.x * blockDim.x + threadIdx.x;
    if (idx >= N * C) return;
    int n = idx / C;
    float w = dinv[n];
    out[idx] = w * w * h[idx];
}

// ---------------- edge scatter: out[dst] += dinv[s]*dinv[d]*h[src] ----------------

template <int C>
__global__ void k_scatter(const int* __restrict__ src, const int* __restrict__ dst,
                          const float* __restrict__ dinv, const float* __restrict__ h,
                          float* __restrict__ out, int E) {
    constexpr int V = C / 4;  // float4 chunks per edge
    int idx = blockIdx.x * blockDim.x + threadIdx.x;
    int e = idx / V;
    if (e >= E) return;
    int c4 = (idx - e * V) * 4;
    int s = src[e], d = dst[e];
    float w = dinv[s] * dinv[d];
    const float4 hv = *reinterpret_cast<const float4*>(h + (size_t)s * C + c4);
    float* o = out + (size_t)d * C + c4;
    atomicAdd(o + 0, w * hv.x);
    atomicAdd(o + 1, w * hv.y);
    atomicAdd(o + 2, w * hv.z);
    atomicAdd(o + 3, w * hv.w);
}

// ---------------- BatchNorm (training stats over rows) ----------------

template <int C>
__global__ void k_bn_stats(const float* __restrict__ xin, float* __restrict__ sums,
                           float* __restrict__ sumsq, int N) {
    constexpr int RPB = 256 / C;  // rows handled per block per iteration
    int t = threadIdx.x;
    int c = t & (C - 1);
    int row = blockIdx.x * RPB + t / C;
    int stride = gridDim.x * RPB;
    float s = 0.f, s2 = 0.f;
    for (; row < N; row += stride) {
        float v = xin[(size_t)row * C + c];
        s += v;
        s2 = fmaf(v, v, s2);
    }
    atomicAdd(&sums[c], s);
    atomicAdd(&sumsq[c], s2);
}

template <int C, bool RELU>
__global__ void k_bn_apply(const float* __restrict__ xin, float* __restrict__ xout,
                           const float* __restrict__ sums, const float* __restrict__ sumsq,
                           const float* __restrict__ g, const float* __restrict__ be,
                           int N, float invN) {
    int idx = blockIdx.x * blockDim.x + threadIdx.x;
    if (idx >= N * C) return;
    int c = idx & (C - 1);
    float m = sums[c] * invN;
    float v = sumsq[c] * invN - m * m;
    float sc = g[c] * rsqrtf(v + 1e-5f);
    float y = (xin[idx] - m) * sc + be[c];
    if (RELU) y = fmaxf(y, 0.f);
    xout[idx] = y;
}

// ---------------- segment_max pooling (values >= 0 post-ReLU -> int atomicMax valid) ----------------

__global__ void k_segmax(const float* __restrict__ act, const int* __restrict__ batch,
                         float* __restrict__ pool, int N) {
    int idx = blockIdx.x * blockDim.x + threadIdx.x;
    if (idx >= N * 128) return;
    int n = idx >> 7, c = idx & 127;
    int b = batch[n];
    atomicMax(reinterpret_cast<int*>(pool) + (b << 7) + c, __float_as_int(act[idx]));
}

// ---------------- head: y = (q @ Wf2 + bf2), row-L2-normalize ----------------

__global__ void k_head(const float* __restrict__ q, const float* __restrict__ Wf2,
                       const float* __restrict__ bf2, float* __restrict__ out) {
    int g = blockIdx.x, c = threadIdx.x;  // 64 threads = 1 wave
    __shared__ float row[128];
    row[c] = q[(g << 7) + c];
    row[c + 64] = q[(g << 7) + 64 + c];
    __syncthreads();
    float acc = bf2[c];
#pragma unroll
    for (int k = 0; k < 128; ++k) acc = fmaf(row[k], Wf2[k * 64 + c], acc);
    float ss = acc * acc;
#pragma unroll
    for (int off = 32; off; off >>= 1) ss += __shfl_xor(ss, off);
    float nrm = sqrtf(ss);
    out[(g << 6) + c] = acc / fmaxf(nrm, 1e-12f);
}

// ---------------- launch ----------------

extern "C" void kernel_launch(void* const* d_in, const int* in_sizes, int n_in,
                              void* d_out, int out_size, void* d_ws, size_t ws_size,
                              hipStream_t stream) {
    const float* x    = (const float*)d_in[0];
    const int*   src  = (const int*)d_in[1];
    const int*   dst  = (const int*)d_in[2];
    const int*   batch= (const int*)d_in[3];
    const float* W1   = (const float*)d_in[4];
    // b1 = d_in[5]  -- cancels in BN
    const float* g1   = (const float*)d_in[6];
    const float* be1  = (const float*)d_in[7];
    const float* W2   = (const float*)d_in[8];
    // b2 = d_in[9]  -- cancels in BN
    const float* g2   = (const float*)d_in[10];
    const float* be2  = (const float*)d_in[11];
    const float* W3   = (const float*)d_in[12];
    // b3 = d_in[13] -- cancels in BN
    const float* g3   = (const float*)d_in[14];
    const float* be3  = (const float*)d_in[15];
    const float* Wf1  = (const float*)d_in[16];
    // bf1 = d_in[17] -- cancels in BN
    const float* g4   = (const float*)d_in[18];
    const float* be4  = (const float*)d_in[19];
    const float* Wf2  = (const float*)d_in[20];
    const float* bf2  = (const float*)d_in[21];
    float* out = (float*)d_out;

    const int N = in_sizes[0] / 6;
    const int E = in_sizes[1];

    // workspace carve-up (all 256B-aligned)
    char* ws = (char*)d_ws;
    size_t off = 0;
    auto carve = [&](size_t bytes) {
        void* p = ws + off;
        off += (bytes + 255) & ~(size_t)255;
        return p;
    };
    int*   cnt   = (int*)carve((size_t)N * 4);
    float* dinv  = (float*)carve((size_t)N * 4);
    float* A     = (float*)carve((size_t)N * 128 * 4);  // matmul output h
    float* B     = (float*)carve((size_t)N * 128 * 4);  // aggregated / activations
    float* stats = (float*)carve(256 * 4);              // sums[128] ++ sumsq[128]
    float* pool  = (float*)carve((size_t)NG * 128 * 4);
    float* Z     = (float*)carve((size_t)NG * 128 * 4);
    float* Q     = (float*)carve((size_t)NG * 128 * 4);
    float* sums  = stats;
    float* sumsq = stats + 128;

    const float invN = 1.0f / (float)N;
    const float invG = 1.0f / (float)NG;

    // degrees
    hipMemsetAsync(cnt, 0, (size_t)N * 4, stream);
    k_count<<<(E + 255) / 256, 256, 0, stream>>>(dst, cnt, E);
    k_dinv<<<(N + 255) / 256, 256, 0, stream>>>(cnt, dinv, N);

    // ---- layer 1: 6 -> 32 ----
    k_matmul<6, 32><<<(N * 32 + 255) / 256, 256, 0, stream>>>(x, W1, A, N);
    k_selfinit<32><<<(N * 32 + 255) / 256, 256, 0, stream>>>(A, dinv, B, N);
    k_scatter<32><<<(E * 8 + 255) / 256, 256, 0, stream>>>(src, dst, dinv, A, B, E);
    hipMemsetAsync(stats, 0, 1024, stream);
    k_bn_stats<32><<<512, 256, 0, stream>>>(B, sums, sumsq, N);
    k_bn_apply<32, true><<<(N * 32 + 255) / 256, 256, 0, stream>>>(B, B, sums, sumsq, g1, be1, N, invN);

    // ---- layer 2: 32 -> 64 ----
    k_matmul<32, 64><<<(N * 64 + 255) / 256, 256, 0, stream>>>(B, W2, A, N);
    k_selfinit<64><<<(N * 64 + 255) / 256, 256, 0, stream>>>(A, dinv, B, N);
    k_scatter<64><<<(E * 16 + 255) / 256, 256, 0, stream>>>(src, dst, dinv, A, B, E);
    hipMemsetAsync(stats, 0, 1024, stream);
    k_bn_stats<64><<<512, 256, 0, stream>>>(B, sums, sumsq, N);
    k_bn_apply<64, true><<<(N * 64 + 255) / 256, 256, 0, stream>>>(B, B, sums, sumsq, g2, be2, N, invN);

    // ---- layer 3: 64 -> 128 ----
    k_matmul<64, 128><<<(N * 128 + 255) / 256, 256, 0, stream>>>(B, W3, A, N);
    k_selfinit<128><<<(N * 128 + 255) / 256, 256, 0, stream>>>(A, dinv, B, N);
    k_scatter<128><<<((size_t)E * 32 + 255) / 256, 256, 0, stream>>>(src, dst, dinv, A, B, E);
    hipMemsetAsync(stats, 0, 1024, stream);
    k_bn_stats<128><<<512, 256, 0, stream>>>(B, sums, sumsq, N);
    k_bn_apply<128, true><<<(N * 128 + 255) / 256, 256, 0, stream>>>(B, B, sums, sumsq, g3, be3, N, invN);

    // ---- pooling: segment_max over sorted batch ----
    hipMemsetAsync(pool, 0, (size_t)NG * 128 * 4, stream);  // post-ReLU values >= 0
    k_segmax<<<(N * 128 + 255) / 256, 256, 0, stream>>>(B, batch, pool, N);

    // ---- head MLP ----
    k_matmul<128, 128><<<(NG * 128 + 255) / 256, 256, 0, stream>>>(pool, Wf1, Z, NG);
    hipMemsetAsync(stats, 0, 1024, stream);
    k_bn_stats<128><<<256, 256, 0, stream>>>(Z, sums, sumsq, NG);
    k_bn_apply<128, true><<<(NG * 128 + 255) / 256, 256, 0, stream>>>(Z, Q, sums, sumsq, g4, be4, NG, invG);

    k_head<<<NG, 64, 0, stream>>>(Q, Wf2, bf2, out);
}

// Round 2
// 1366.642 us; speedup vs baseline: 4.0065x; 4.0065x over previous
//
#include <hip/hip_runtime.h>
#include <hip/hip_bf16.h>

#define NG 512  // NUM_GRAPHS

// ---------------- degree / normalization ----------------

__global__ void k_count(const int* __restrict__ dst, int* __restrict__ cnt, int E) {
    int i = blockIdx.x * blockDim.x + threadIdx.x;
    if (i < E) atomicAdd(&cnt[dst[i]], 1);
}

__global__ void k_dinv(const int* __restrict__ cnt, float* __restrict__ dinv, int N) {
    int i = blockIdx.x * blockDim.x + threadIdx.x;
    if (i < N) dinv[i] = rsqrtf((float)cnt[i] + 1.0f);  // +1 self-loop; deg>=1 always
}

// ---------------- exclusive prefix-sum over cnt -> rowptr (3-kernel scan) ----------------

#define SCAN_T 256
#define SCAN_I 4  // 1024 elements per block

__global__ void k_scan1(const int* __restrict__ in, int* __restrict__ out,
                        int* __restrict__ bsum, int N) {
    __shared__ int lds[SCAN_T];
    int t = threadIdx.x;
    int base = blockIdx.x * (SCAN_T * SCAN_I) + t * SCAN_I;
    int v[SCAN_I];
    int sum = 0;
#pragma unroll
    for (int i = 0; i < SCAN_I; ++i) {
        int idx = base + i;
        v[i] = (idx < N) ? in[idx] : 0;
        sum += v[i];
    }
    lds[t] = sum;
    __syncthreads();
    for (int o = 1; o < SCAN_T; o <<= 1) {
        int a = (t >= o) ? lds[t - o] : 0;
        __syncthreads();
        lds[t] += a;
        __syncthreads();
    }
    int run = lds[t] - sum;  // exclusive prefix of this thread's chunk
#pragma unroll
    for (int i = 0; i < SCAN_I; ++i) {
        int idx = base + i;
        if (idx < N) out[idx] = run;
        run += v[i];
    }
    if (t == SCAN_T - 1) bsum[blockIdx.x] = lds[SCAN_T - 1];
}

__global__ void k_scan2(int* __restrict__ bs, int nb) {
    __shared__ int lds[SCAN_T];
    int t = threadIdx.x;
    int runbase = 0;
    for (int start = 0; start < nb; start += SCAN_T) {
        int idx = start + t;
        int v = (idx < nb) ? bs[idx] : 0;
        lds[t] = v;
        __syncthreads();
        for (int o = 1; o < SCAN_T; o <<= 1) {
            int a = (t >= o) ? lds[t - o] : 0;
            __syncthreads();
            lds[t] += a;
            __syncthreads();
        }
        if (idx < nb) bs[idx] = runbase + lds[t] - v;  // exclusive
        int tot = lds[SCAN_T - 1];
        __syncthreads();
        runbase += tot;
    }
}

__global__ void k_scan3(int* __restrict__ out, const int* __restrict__ bs, int N) {
    int add = bs[blockIdx.x];
    int base = blockIdx.x * (SCAN_T * SCAN_I) + threadIdx.x * SCAN_I;
#pragma unroll
    for (int i = 0; i < SCAN_I; ++i) {
        int idx = base + i;
        if (idx < N) out[idx] += add;
    }
}

// ---------------- bucket edges by dst (CSR), pre-bake per-edge weight dinv[src] ----------------

__global__ void k_bucket(const int* __restrict__ src, const int* __restrict__ dst,
                         const float* __restrict__ dinv, const int* __restrict__ rowptr,
                         int* __restrict__ fill, int* __restrict__ esrc,
                         float* __restrict__ ewt, int E) {
    int e = blockIdx.x * blockDim.x + threadIdx.x;
    if (e >= E) return;
    int d = dst[e], s = src[e];
    int pos = rowptr[d] + atomicAdd(&fill[d], 1);
    esrc[pos] = s;
    ewt[pos] = dinv[s];
}

// ---------------- dense matmul (small channel counts, per-thread dot) ----------------

template <int CIN, int COUT>
__global__ void k_matmul(const float* __restrict__ in, const float* __restrict__ W,
                         float* __restrict__ h, int N) {
    int idx = blockIdx.x * blockDim.x + threadIdx.x;
    int n = idx / COUT;
    if (n >= N) return;
    int c = idx - n * COUT;
    float acc = 0.f;
#pragma unroll
    for (int k = 0; k < CIN; ++k) acc = fmaf(in[n * CIN + k], W[k * COUT + c], acc);
    h[idx] = acc;
}

// ---------------- fused GCN aggregation (gather form, no atomics) ----------------
// out[d][c] = dinv[d] * ( dinv[d]*h[d][c] + sum_e dinv[src_e]*h[src_e][c] )

template <int C>
__global__ void k_gather(const int* __restrict__ rowptr, const int* __restrict__ cnt,
                         const int* __restrict__ esrc, const float* __restrict__ ewt,
                         const float* __restrict__ dinv, const float* __restrict__ h,
                         float* __restrict__ out, int N) {
    constexpr int NPB = 256 / C;  // nodes per block
    int t = threadIdx.x;
    int c = t & (C - 1);
    int n = blockIdx.x * NPB + t / C;
    if (n >= N) return;
    int beg = rowptr[n];
    int end = beg + cnt[n];
    float di = dinv[n];
    float acc = di * h[(size_t)n * C + c];  // self-loop term
    for (int e = beg; e < end; ++e) {
        acc = fmaf(ewt[e], h[(size_t)esrc[e] * C + c], acc);
    }
    out[(size_t)n * C + c] = di * acc;
}

// ---------------- BatchNorm (training stats over rows) ----------------

template <int C>
__global__ void k_bn_stats(const float* __restrict__ xin, float* __restrict__ sums,
                           float* __restrict__ sumsq, int N) {
    constexpr int RPB = 256 / C;
    int t = threadIdx.x;
    int c = t & (C - 1);
    int row = blockIdx.x * RPB + t / C;
    int stride = gridDim.x * RPB;
    float s = 0.f, s2 = 0.f;
    for (; row < N; row += stride) {
        float v = xin[(size_t)row * C + c];
        s += v;
        s2 = fmaf(v, v, s2);
    }
    atomicAdd(&sums[c], s);
    atomicAdd(&sumsq[c], s2);
}

template <int C, bool RELU>
__global__ void k_bn_apply(const float* __restrict__ xin, float* __restrict__ xout,
                           const float* __restrict__ sums, const float* __restrict__ sumsq,
                           const float* __restrict__ g, const float* __restrict__ be,
                           int N, float invN) {
    int idx = blockIdx.x * blockDim.x + threadIdx.x;
    if (idx >= N * C) return;
    int c = idx & (C - 1);
    float m = sums[c] * invN;
    float v = sumsq[c] * invN - m * m;
    float sc = g[c] * rsqrtf(v + 1e-5f);
    float y = (xin[idx] - m) * sc + be[c];
    if (RELU) y = fmaxf(y, 0.f);
    xout[idx] = y;
}

// ---------------- segment_max pooling (values >= 0 post-ReLU -> int atomicMax valid) ----------------

__global__ void k_segmax(const float* __restrict__ act, const int* __restrict__ batch,
                         float* __restrict__ pool, int N) {
    int idx = blockIdx.x * blockDim.x + threadIdx.x;
    if (idx >= N * 128) return;
    int n = idx >> 7, c = idx & 127;
    int b = batch[n];
    atomicMax(reinterpret_cast<int*>(pool) + (b << 7) + c, __float_as_int(act[idx]));
}

// ---------------- head: y = (q @ Wf2 + bf2), row-L2-normalize ----------------

__global__ void k_head(const float* __restrict__ q, const float* __restrict__ Wf2,
                       const float* __restrict__ bf2, float* __restrict__ out) {
    int g = blockIdx.x, c = threadIdx.x;  // 64 threads = 1 wave
    __shared__ float row[128];
    row[c] = q[(g << 7) + c];
    row[c + 64] = q[(g << 7) + 64 + c];
    __syncthreads();
    float acc = bf2[c];
#pragma unroll
    for (int k = 0; k < 128; ++k) acc = fmaf(row[k], Wf2[k * 64 + c], acc);
    float ss = acc * acc;
#pragma unroll
    for (int off = 32; off; off >>= 1) ss += __shfl_xor(ss, off);
    float nrm = sqrtf(ss);
    out[(g << 6) + c] = acc / fmaxf(nrm, 1e-12f);
}

// ---------------- launch ----------------

extern "C" void kernel_launch(void* const* d_in, const int* in_sizes, int n_in,
                              void* d_out, int out_size, void* d_ws, size_t ws_size,
                              hipStream_t stream) {
    const float* x    = (const float*)d_in[0];
    const int*   src  = (const int*)d_in[1];
    const int*   dst  = (const int*)d_in[2];
    const int*   batch= (const int*)d_in[3];
    const float* W1   = (const float*)d_in[4];
    const float* g1   = (const float*)d_in[6];
    const float* be1  = (const float*)d_in[7];
    const float* W2   = (const float*)d_in[8];
    const float* g2   = (const float*)d_in[10];
    const float* be2  = (const float*)d_in[11];
    const float* W3   = (const float*)d_in[12];
    const float* g3   = (const float*)d_in[14];
    const float* be3  = (const float*)d_in[15];
    const float* Wf1  = (const float*)d_in[16];
    const float* g4   = (const float*)d_in[18];
    const float* be4  = (const float*)d_in[19];
    const float* Wf2  = (const float*)d_in[20];
    const float* bf2  = (const float*)d_in[21];
    float* out = (float*)d_out;

    const int N = in_sizes[0] / 6;
    const int E = in_sizes[1];
    const int nScanBlocks = (N + SCAN_T * SCAN_I - 1) / (SCAN_T * SCAN_I);

    // workspace carve-up (all 256B-aligned)
    char* ws = (char*)d_ws;
    size_t off = 0;
    auto carve = [&](size_t bytes) {
        void* p = ws + off;
        off += (bytes + 255) & ~(size_t)255;
        return p;
    };
    int*   cnt    = (int*)carve((size_t)N * 4);
    float* dinv   = (float*)carve((size_t)N * 4);
    int*   rowptr = (int*)carve((size_t)N * 4);
    int*   fill   = (int*)carve((size_t)N * 4);
    int*   bsum   = (int*)carve((size_t)4096 * 4);
    int*   esrc   = (int*)carve((size_t)E * 4);
    float* ewt    = (float*)carve((size_t)E * 4);
    float* A      = (float*)carve((size_t)N * 128 * 4);  // matmul output h
    float* B      = (float*)carve((size_t)N * 128 * 4);  // aggregated / activations
    float* stats  = (float*)carve(256 * 4);              // sums[128] ++ sumsq[128]
    float* pool   = (float*)carve((size_t)NG * 128 * 4);
    float* Z      = (float*)carve((size_t)NG * 128 * 4);
    float* Q      = (float*)carve((size_t)NG * 128 * 4);
    float* sums  = stats;
    float* sumsq = stats + 128;

    const float invN = 1.0f / (float)N;
    const float invG = 1.0f / (float)NG;

    // ---- build dst-sorted CSR (once; reused by all 3 layers) ----
    hipMemsetAsync(cnt, 0, (size_t)N * 4, stream);
    hipMemsetAsync(fill, 0, (size_t)N * 4, stream);
    k_count<<<(E + 255) / 256, 256, 0, stream>>>(dst, cnt, E);
    k_dinv<<<(N + 255) / 256, 256, 0, stream>>>(cnt, dinv, N);
    k_scan1<<<nScanBlocks, SCAN_T, 0, stream>>>(cnt, rowptr, bsum, N);
    k_scan2<<<1, SCAN_T, 0, stream>>>(bsum, nScanBlocks);
    k_scan3<<<nScanBlocks, SCAN_T, 0, stream>>>(rowptr, bsum, N);
    k_bucket<<<(E + 255) / 256, 256, 0, stream>>>(src, dst, dinv, rowptr, fill, esrc, ewt, E);

    // ---- layer 1: 6 -> 32 ----
    k_matmul<6, 32><<<(N * 32 + 255) / 256, 256, 0, stream>>>(x, W1, A, N);
    k_gather<32><<<(N * 32 + 255) / 256, 256, 0, stream>>>(rowptr, cnt, esrc, ewt, dinv, A, B, N);
    hipMemsetAsync(stats, 0, 1024, stream);
    k_bn_stats<32><<<512, 256, 0, stream>>>(B, sums, sumsq, N);
    k_bn_apply<32, true><<<(N * 32 + 255) / 256, 256, 0, stream>>>(B, B, sums, sumsq, g1, be1, N, invN);

    // ---- layer 2: 32 -> 64 ----
    k_matmul<32, 64><<<(N * 64 + 255) / 256, 256, 0, stream>>>(B, W2, A, N);
    k_gather<64><<<(N * 64 + 255) / 256, 256, 0, stream>>>(rowptr, cnt, esrc, ewt, dinv, A, B, N);
    hipMemsetAsync(stats, 0, 1024, stream);
    k_bn_stats<64><<<512, 256, 0, stream>>>(B, sums, sumsq, N);
    k_bn_apply<64, true><<<(N * 64 + 255) / 256, 256, 0, stream>>>(B, B, sums, sumsq, g2, be2, N, invN);

    // ---- layer 3: 64 -> 128 ----
    k_matmul<64, 128><<<(N * 128 + 255) / 256, 256, 0, stream>>>(B, W3, A, N);
    k_gather<128><<<(N * 128 + 255) / 256, 256, 0, stream>>>(rowptr, cnt, esrc, ewt, dinv, A, B, N);
    hipMemsetAsync(stats, 0, 1024, stream);
    k_bn_stats<128><<<512, 256, 0, stream>>>(B, sums, sumsq, N);
    k_bn_apply<128, true><<<(N * 128 + 255) / 256, 256, 0, stream>>>(B, B, sums, sumsq, g3, be3, N, invN);

    // ---- pooling: segment_max over sorted batch ----
    hipMemsetAsync(pool, 0, (size_t)NG * 128 * 4, stream);  // post-ReLU values >= 0
    k_segmax<<<(N * 128 + 255) / 256, 256, 0, stream>>>(B, batch, pool, N);

    // ---- head MLP ----
    k_matmul<128, 128><<<(NG * 128 + 255) / 256, 256, 0, stream>>>(pool, Wf1, Z, NG);
    hipMemsetAsync(stats, 0, 1024, stream);
    k_bn_stats<128><<<256, 256, 0, stream>>>(Z, sums, sumsq, NG);
    k_bn_apply<128, true><<<(NG * 128 + 255) / 256, 256, 0, stream>>>(Z, Q, sums, sumsq, g4, be4, NG, invG);

    k_head<<<NG, 64, 0, stream>>>(Q, Wf2, bf2, out);
}

// Round 3
// 1206.812 us; speedup vs baseline: 4.5372x; 1.1324x over previous
//
#include <hip/hip_runtime.h>
#include <hip/hip_bf16.h>

#define NG 512  // NUM_GRAPHS
#define EPS_BN 1e-5f

__device__ __forceinline__ float4 f4add(float4 a, float4 b) {
    a.x += b.x; a.y += b.y; a.z += b.z; a.w += b.w; return a;
}
__device__ __forceinline__ float4 f4fma(float s, float4 b, float4 a) {
    a.x = fmaf(s, b.x, a.x); a.y = fmaf(s, b.y, a.y);
    a.z = fmaf(s, b.z, a.z); a.w = fmaf(s, b.w, a.w); return a;
}

// ---------------- degree / normalization ----------------

__global__ void k_count(const int* __restrict__ dst, int* __restrict__ cnt, int E) {
    int i = blockIdx.x * blockDim.x + threadIdx.x;
    if (i < E) atomicAdd(&cnt[dst[i]], 1);
}

__global__ void k_dinv(const int* __restrict__ cnt, float* __restrict__ dinv, int N) {
    int i = blockIdx.x * blockDim.x + threadIdx.x;
    if (i < N) dinv[i] = rsqrtf((float)cnt[i] + 1.0f);  // +1 self-loop
}

// ---------------- exclusive prefix-sum over cnt -> rowptr ----------------

#define SCAN_T 256
#define SCAN_I 4  // 1024 elements per block

__global__ void k_scan1(const int* __restrict__ in, int* __restrict__ out,
                        int* __restrict__ bsum, int N) {
    __shared__ int lds[SCAN_T];
    int t = threadIdx.x;
    int base = blockIdx.x * (SCAN_T * SCAN_I) + t * SCAN_I;
    int v[SCAN_I];
    int sum = 0;
#pragma unroll
    for (int i = 0; i < SCAN_I; ++i) {
        int idx = base + i;
        v[i] = (idx < N) ? in[idx] : 0;
        sum += v[i];
    }
    lds[t] = sum;
    __syncthreads();
    for (int o = 1; o < SCAN_T; o <<= 1) {
        int a = (t >= o) ? lds[t - o] : 0;
        __syncthreads();
        lds[t] += a;
        __syncthreads();
    }
    int run = lds[t] - sum;
#pragma unroll
    for (int i = 0; i < SCAN_I; ++i) {
        int idx = base + i;
        if (idx < N) out[idx] = run;
        run += v[i];
    }
    if (t == SCAN_T - 1) bsum[blockIdx.x] = lds[SCAN_T - 1];
}

__global__ void k_scan2(int* __restrict__ bs, int nb) {
    __shared__ int lds[SCAN_T];
    int t = threadIdx.x;
    int runbase = 0;
    for (int start = 0; start < nb; start += SCAN_T) {
        int idx = start + t;
        int v = (idx < nb) ? bs[idx] : 0;
        lds[t] = v;
        __syncthreads();
        for (int o = 1; o < SCAN_T; o <<= 1) {
            int a = (t >= o) ? lds[t - o] : 0;
            __syncthreads();
            lds[t] += a;
            __syncthreads();
        }
        if (idx < nb) bs[idx] = runbase + lds[t] - v;
        int tot = lds[SCAN_T - 1];
        __syncthreads();
        runbase += tot;
    }
}

__global__ void k_scan3(int* __restrict__ out, const int* __restrict__ bs, int N) {
    int add = bs[blockIdx.x];
    int base = blockIdx.x * (SCAN_T * SCAN_I) + threadIdx.x * SCAN_I;
#pragma unroll
    for (int i = 0; i < SCAN_I; ++i) {
        int idx = base + i;
        if (idx < N) out[idx] += add;
    }
}

// ---------------- bucket edges by dst (CSR), pre-bake per-edge weight dinv[src] ----------------

__global__ void k_bucket(const int* __restrict__ src, const int* __restrict__ dst,
                         const float* __restrict__ dinv, const int* __restrict__ rowptr,
                         int* __restrict__ fill, int* __restrict__ esrc,
                         float* __restrict__ ewt, int E) {
    int e = blockIdx.x * blockDim.x + threadIdx.x;
    if (e >= E) return;
    int d = dst[e], s = src[e];
    int pos = rowptr[d] + atomicAdd(&fill[d], 1);
    esrc[pos] = s;
    ewt[pos] = dinv[s];
}

// ---------------- gather over raw x (layer 1 input, C=6, no BN) ----------------
// out[d][c] = dinv[d] * ( dinv[d]*x[d][c] + sum_e dinv[src]*x[src][c] )

__global__ void k_gather_x(const int* __restrict__ rowptr, const int* __restrict__ cnt,
                           const int* __restrict__ esrc, const float* __restrict__ ewt,
                           const float* __restrict__ dinv, const float* __restrict__ x,
                           float* __restrict__ out, int N) {
    int t = threadIdx.x;
    int c = t & 7;
    int n = blockIdx.x * 32 + (t >> 3);
    if (n >= N || c >= 6) return;
    int beg = rowptr[n], end = beg + cnt[n];
    float di = dinv[n];
    float acc = di * x[(size_t)n * 6 + c];
    int e = beg;
    for (; e + 1 < end; e += 2) {
        int s0 = esrc[e], s1 = esrc[e + 1];
        float w0 = ewt[e], w1 = ewt[e + 1];
        float v0 = x[(size_t)s0 * 6 + c];
        float v1 = x[(size_t)s1 * 6 + c];
        acc = fmaf(w0, v0, fmaf(w1, v1, acc));
    }
    if (e < end) acc = fmaf(ewt[e], x[(size_t)esrc[e] * 6 + c], acc);
    out[(size_t)n * 6 + c] = di * acc;
}

// ---------------- gather with fused BN+ReLU applied to the loaded values ----------------

template <int C>
__global__ void k_gather_bn(const int* __restrict__ rowptr, const int* __restrict__ cnt,
                            const int* __restrict__ esrc, const float* __restrict__ ewt,
                            const float* __restrict__ dinv, const float* __restrict__ h,
                            const float* __restrict__ sums, const float* __restrict__ sumsq,
                            const float* __restrict__ gam, const float* __restrict__ bet,
                            float* __restrict__ out, int N, float invN) {
    int t = threadIdx.x;
    int c = t & (C - 1);
    int n = blockIdx.x * (256 / C) + t / C;
    if (n >= N) return;
    float m = sums[c] * invN;
    float var = fmaf(-m, m, sumsq[c] * invN);
    float sc = gam[c] * rsqrtf(var + EPS_BN);
    float sh = fmaf(-m, sc, bet[c]);
    int beg = rowptr[n], end = beg + cnt[n];
    float di = dinv[n];
    float acc = di * fmaxf(fmaf(sc, h[(size_t)n * C + c], sh), 0.f);  // self-loop
    int e = beg;
    for (; e + 1 < end; e += 2) {
        int s0 = esrc[e], s1 = esrc[e + 1];
        float w0 = ewt[e], w1 = ewt[e + 1];
        float v0 = fmaxf(fmaf(sc, h[(size_t)s0 * C + c], sh), 0.f);
        float v1 = fmaxf(fmaf(sc, h[(size_t)s1 * C + c], sh), 0.f);
        acc = fmaf(w0, v0, fmaf(w1, v1, acc));
    }
    if (e < end)
        acc = fmaf(ewt[e], fmaxf(fmaf(sc, h[(size_t)esrc[e] * C + c], sh), 0.f), acc);
    out[(size_t)n * C + c] = di * acc;
}

// ---------------- matmul with fused BN-stats (grid-stride, float4, LDS reduce) ----------------

template <int CIN, int COUT>
__global__ void k_mm_stats(const float* __restrict__ in, const float* __restrict__ W,
                           float* __restrict__ out, float* __restrict__ sums,
                           float* __restrict__ sumsq, int N) {
    constexpr int CG = COUT / 4;    // channel groups of 4
    constexpr int RPB = 256 / CG;   // rows per block-iteration
    int t = threadIdx.x;
    int gi = t % CG;
    int r0 = t / CG;
    int c0 = gi * 4;
    const float4* W4 = reinterpret_cast<const float4*>(W);
    float4 s = {0, 0, 0, 0}, s2 = {0, 0, 0, 0};
    int stride = gridDim.x * RPB;
    for (int row = blockIdx.x * RPB + r0; row < N; row += stride) {
        float4 acc = {0, 0, 0, 0};
        if constexpr (CIN % 4 == 0) {
            const float4* in4 = reinterpret_cast<const float4*>(in + (size_t)row * CIN);
#pragma unroll
            for (int k4 = 0; k4 < CIN / 4; ++k4) {
                float4 v = in4[k4];
                acc = f4fma(v.x, W4[(k4 * 4 + 0) * CG + gi], acc);
                acc = f4fma(v.y, W4[(k4 * 4 + 1) * CG + gi], acc);
                acc = f4fma(v.z, W4[(k4 * 4 + 2) * CG + gi], acc);
                acc = f4fma(v.w, W4[(k4 * 4 + 3) * CG + gi], acc);
            }
        } else {
#pragma unroll
            for (int k = 0; k < CIN; ++k)
                acc = f4fma(in[(size_t)row * CIN + k], W4[k * CG + gi], acc);
        }
        reinterpret_cast<float4*>(out + (size_t)row * COUT)[gi] = acc;
        s = f4add(s, acc);
        s2.x = fmaf(acc.x, acc.x, s2.x);
        s2.y = fmaf(acc.y, acc.y, s2.y);
        s2.z = fmaf(acc.z, acc.z, s2.z);
        s2.w = fmaf(acc.w, acc.w, s2.w);
    }
    __shared__ float4 ls[256];
    __shared__ float4 ls2[256];
    ls[t] = s; ls2[t] = s2;
    for (int h = RPB / 2; h > 0; h >>= 1) {
        __syncthreads();
        if (r0 < h) {
            ls[t] = f4add(ls[t], ls[t + h * CG]);
            ls2[t] = f4add(ls2[t], ls2[t + h * CG]);
        }
    }
    if (r0 == 0) {
        float4 a = ls[t], b = ls2[t];
        atomicAdd(&sums[c0 + 0], a.x); atomicAdd(&sums[c0 + 1], a.y);
        atomicAdd(&sums[c0 + 2], a.z); atomicAdd(&sums[c0 + 3], a.w);
        atomicAdd(&sumsq[c0 + 0], b.x); atomicAdd(&sumsq[c0 + 1], b.y);
        atomicAdd(&sumsq[c0 + 2], b.z); atomicAdd(&sumsq[c0 + 3], b.w);
    }
}

// ---------------- segmented segment_max with fused BN+ReLU (batch is sorted) ----------------

__global__ void k_segmax_bn(const float* __restrict__ h, const int* __restrict__ batch,
                            const float* __restrict__ sums, const float* __restrict__ sumsq,
                            const float* __restrict__ gam, const float* __restrict__ bet,
                            float* __restrict__ pool, int N, float invN) {
    int t = threadIdx.x;
    int c = t & 127;
    int sub = t >> 7;
    int base = blockIdx.x * 64 + sub * 32;
    if (base >= N) return;
    float m = sums[c] * invN;
    float var = fmaf(-m, m, sumsq[c] * invN);
    float sc = gam[c] * rsqrtf(var + EPS_BN);
    float sh = fmaf(-m, sc, bet[c]);
    int cur = batch[base];
    float mx = fmaxf(fmaf(sc, h[(size_t)base * 128 + c], sh), 0.f);
    int lim = min(32, N - base);
    for (int i = 1; i < lim; ++i) {
        int n = base + i;
        int b = batch[n];
        float v = fmaxf(fmaf(sc, h[(size_t)n * 128 + c], sh), 0.f);
        if (b != cur) {  // uniform across the 128 lanes of this sub-chunk
            atomicMax(reinterpret_cast<int*>(pool) + (cur << 7) + c, __float_as_int(mx));
            cur = b; mx = v;
        } else {
            mx = fmaxf(mx, v);
        }
    }
    atomicMax(reinterpret_cast<int*>(pool) + (cur << 7) + c, __float_as_int(mx));
}

// ---------------- head: BN4+ReLU on load, FC2, row-L2-normalize ----------------

__global__ void k_head(const float* __restrict__ Z, const float* __restrict__ sums,
                       const float* __restrict__ sumsq, const float* __restrict__ gam,
                       const float* __restrict__ bet, const float* __restrict__ Wf2,
                       const float* __restrict__ bf2, float* __restrict__ out) {
    int g = blockIdx.x, c = threadIdx.x;  // 64 threads = 1 wave
    __shared__ float row[128];
    const float invG = 1.0f / (float)NG;
    for (int j = c; j < 128; j += 64) {
        float m = sums[j] * invG;
        float var = fmaf(-m, m, sumsq[j] * invG);
        float sc = gam[j] * rsqrtf(var + EPS_BN);
        float sh = fmaf(-m, sc, bet[j]);
        row[j] = fmaxf(fmaf(sc, Z[(g << 7) + j], sh), 0.f);
    }
    __syncthreads();
    float acc = bf2[c];
#pragma unroll
    for (int k = 0; k < 128; ++k) acc = fmaf(row[k], Wf2[k * 64 + c], acc);
    float ss = acc * acc;
#pragma unroll
    for (int off = 32; off; off >>= 1) ss += __shfl_xor(ss, off);
    out[(g << 6) + c] = acc / fmaxf(sqrtf(ss), 1e-12f);
}

// ---------------- launch ----------------

extern "C" void kernel_launch(void* const* d_in, const int* in_sizes, int n_in,
                              void* d_out, int out_size, void* d_ws, size_t ws_size,
                              hipStream_t stream) {
    const float* x    = (const float*)d_in[0];
    const int*   src  = (const int*)d_in[1];
    const int*   dst  = (const int*)d_in[2];
    const int*   batch= (const int*)d_in[3];
    const float* W1   = (const float*)d_in[4];   // b1 cancels in BN
    const float* g1   = (const float*)d_in[6];
    const float* be1  = (const float*)d_in[7];
    const float* W2   = (const float*)d_in[8];   // b2 cancels
    const float* g2   = (const float*)d_in[10];
    const float* be2  = (const float*)d_in[11];
    const float* W3   = (const float*)d_in[12];  // b3 cancels
    const float* g3   = (const float*)d_in[14];
    const float* be3  = (const float*)d_in[15];
    const float* Wf1  = (const float*)d_in[16];  // bf1 cancels
    const float* g4   = (const float*)d_in[18];
    const float* be4  = (const float*)d_in[19];
    const float* Wf2  = (const float*)d_in[20];
    const float* bf2  = (const float*)d_in[21];
    float* out = (float*)d_out;

    const int N = in_sizes[0] / 6;
    const int E = in_sizes[1];
    const int nScanBlocks = (N + SCAN_T * SCAN_I - 1) / (SCAN_T * SCAN_I);

    // workspace carve-up
    char* ws = (char*)d_ws;
    size_t off = 0;
    auto carve = [&](size_t bytes) {
        void* p = ws + off;
        off += (bytes + 255) & ~(size_t)255;
        return p;
    };
    int*   cnt    = (int*)carve((size_t)N * 4);
    float* dinv   = (float*)carve((size_t)N * 4);
    int*   rowptr = (int*)carve((size_t)N * 4);
    int*   fill   = (int*)carve((size_t)N * 4);
    int*   bsum   = (int*)carve((size_t)4096 * 4);
    int*   esrc   = (int*)carve((size_t)E * 4);
    float* ewt    = (float*)carve((size_t)E * 4);
    float* G      = (float*)carve((size_t)N * 64 * 4);   // gather outputs (max C=64)
    float* H      = (float*)carve((size_t)N * 128 * 4);  // matmul outputs (max C=128)
    float* stats  = (float*)carve(704 * 4);
    float* pool   = (float*)carve((size_t)NG * 128 * 4);
    float* Z      = (float*)carve((size_t)NG * 128 * 4);
    // stats layout: L1 sums/sumsq (32+32), L2 (64+64), L3 (128+128), head (128+128)
    float* s1 = stats;        // [0,64)
    float* s2 = stats + 64;   // [64,192)
    float* s3 = stats + 192;  // [192,448)
    float* s4 = stats + 448;  // [448,704)

    const float invN = 1.0f / (float)N;

    // ---- build dst-sorted CSR (once; reused by all 3 layers) ----
    hipMemsetAsync(cnt, 0, (size_t)N * 4, stream);
    hipMemsetAsync(fill, 0, (size_t)N * 4, stream);
    hipMemsetAsync(stats, 0, 704 * 4, stream);
    hipMemsetAsync(pool, 0, (size_t)NG * 128 * 4, stream);
    k_count<<<(E + 255) / 256, 256, 0, stream>>>(dst, cnt, E);
    k_dinv<<<(N + 255) / 256, 256, 0, stream>>>(cnt, dinv, N);
    k_scan1<<<nScanBlocks, SCAN_T, 0, stream>>>(cnt, rowptr, bsum, N);
    k_scan2<<<1, SCAN_T, 0, stream>>>(bsum, nScanBlocks);
    k_scan3<<<nScanBlocks, SCAN_T, 0, stream>>>(rowptr, bsum, N);
    k_bucket<<<(E + 255) / 256, 256, 0, stream>>>(src, dst, dinv, rowptr, fill, esrc, ewt, E);

    // ---- layer 1: aggregate x (C=6), then 6->32 matmul (+stats1) ----
    k_gather_x<<<(N + 31) / 32, 256, 0, stream>>>(rowptr, cnt, esrc, ewt, dinv, x, G, N);
    k_mm_stats<6, 32><<<1024, 256, 0, stream>>>(G, W1, H, s1, s1 + 32, N);

    // ---- layer 2: aggregate act1(h1) (C=32), then 32->64 matmul (+stats2) ----
    k_gather_bn<32><<<(N * 32 + 255) / 256, 256, 0, stream>>>(
        rowptr, cnt, esrc, ewt, dinv, H, s1, s1 + 32, g1, be1, G, N, invN);
    k_mm_stats<32, 64><<<1024, 256, 0, stream>>>(G, W2, H, s2, s2 + 64, N);

    // ---- layer 3: aggregate act2(h2) (C=64), then 64->128 matmul (+stats3) ----
    k_gather_bn<64><<<(N * 64 + 255) / 256, 256, 0, stream>>>(
        rowptr, cnt, esrc, ewt, dinv, H, s2, s2 + 64, g2, be2, G, N, invN);
    k_mm_stats<64, 128><<<1024, 256, 0, stream>>>(G, W3, H, s3, s3 + 128, N);

    // ---- pooling: segmented segment_max with fused BN3+ReLU ----
    k_segmax_bn<<<(N + 63) / 64, 256, 0, stream>>>(H, batch, s3, s3 + 128, g3, be3, pool, N, invN);

    // ---- head: FC1 (+stats4), then BN4+ReLU+FC2+normalize ----
    k_mm_stats<128, 128><<<64, 256, 0, stream>>>(pool, Wf1, Z, s4, s4 + 128, NG);
    k_head<<<NG, 64, 0, stream>>>(Z, s4, s4 + 128, g4, be4, Wf2, bf2, out);
}